// Round 2
// baseline (602.643 us; speedup 1.0000x reference)
//
#include <hip/hip_runtime.h>
#include <stdint.h>

#define BB 8
#define CC 16
#define HH 96
#define WW 96
#define HID 128
#define HW (HH*WW)            // 9216
#define CHW (CC*HW)           // 147456
#define NPIX (BB*HW)          // 73728
#define STEPS 16

// ---------------- Threefry-2x32 (JAX-compatible, 20 rounds) ----------------
__host__ __device__ inline void threefry2x32(uint32_t k0, uint32_t k1,
                                             uint32_t x0, uint32_t x1,
                                             uint32_t& o0, uint32_t& o1) {
  const uint32_t ks2 = k0 ^ k1 ^ 0x1BD11BDAu;
  uint32_t v0 = x0 + k0, v1 = x1 + k1;
#define RL(v, r) (((v) << (r)) | ((v) >> (32 - (r))))
#define RND(r) { v0 += v1; v1 = RL(v1, r); v1 ^= v0; }
  RND(13) RND(15) RND(26) RND(6)   v0 += k1;  v1 += ks2 + 1u;
  RND(17) RND(29) RND(16) RND(24)  v0 += ks2; v1 += k0 + 2u;
  RND(13) RND(15) RND(26) RND(6)   v0 += k0;  v1 += k1 + 3u;
  RND(17) RND(29) RND(16) RND(24)  v0 += k1;  v1 += ks2 + 4u;
  RND(13) RND(15) RND(26) RND(6)   v0 += ks2; v1 += k0 + 5u;
#undef RND
#undef RL
  o0 = v0; o1 = v1;
}

// fire mask: jax.random.uniform(key_i, (B,1,H,W)) < 0.5
// partitionable threefry (JAX >= 0.4.30 default): per element j,
//   bits[j] = x0 ^ x1 of threefry(key_i, (hi=0, lo=j))   <-- XOR of BOTH words
//   u < 0.5  <=>  top bit of bits is 0
__device__ inline float fire_val(uint32_t ka, uint32_t kb, uint32_t j) {
  uint32_t r0, r1;
  threefry2x32(ka, kb, 0u, j, r0, r1);
  const uint32_t bits = r0 ^ r1;   // RNG VARIANT: partitionable, x0^x1
  return (bits & 0x80000000u) ? 0.0f : 1.0f;
}

// ---------------- w2 transpose: (16,128) -> (128,16) ----------------
__global__ void transp_w2(const float* __restrict__ w2, float* __restrict__ w2t) {
  int i = threadIdx.x + blockIdx.x * blockDim.x;
  if (i < CC * HID) {
    int o = i / HID, k = i - o * HID;
    w2t[k * CC + o] = w2[i];
  }
}

// ---------------- Kernel A: perception + MLP + fire -> raw ----------------
// block = 256 threads = 4 waves; each wave handles the SAME 64 pixels and a
// quarter (32) of the hidden units; LDS reduction combines quarters.
__global__ __launch_bounds__(256) void ca_update(
    const float* __restrict__ xcur, const float* __restrict__ w1,
    const float* __restrict__ b1,   const float* __restrict__ w2t,
    const float* __restrict__ b2,   float* __restrict__ raw,
    uint32_t ka, uint32_t kb)
{
  __shared__ float red[4][CC][64];   // [quarter][channel][pixel-lane] : 16 KiB
  const int tid  = threadIdx.x;
  const int lane = tid & 63;
  const int q    = __builtin_amdgcn_readfirstlane(tid >> 6);  // wave-uniform
  const int P    = blockIdx.x * 64 + lane;
  const int b    = P / HW;
  const int rem  = P - b * HW;
  const int h    = rem / WW;
  const int w    = rem - h * WW;

  // ---- perception: p = [x, grad_x, grad_y] (sobel/8, correlation, zero-pad)
  float p[3 * CC];
  const float* xb = xcur + b * CHW + h * WW + w;
  const bool hm = (h > 0), hp = (h < HH - 1), wm = (w > 0), wp = (w < WW - 1);
#pragma unroll
  for (int c = 0; c < CC; ++c) {
    const float* xc = xb + c * HW;
    float v00 = (hm && wm) ? xc[-WW - 1] : 0.f;
    float v01 = (hm      ) ? xc[-WW    ] : 0.f;
    float v02 = (hm && wp) ? xc[-WW + 1] : 0.f;
    float v10 = (wm      ) ? xc[-1]      : 0.f;
    float v11 =              xc[0];
    float v12 = (wp      ) ? xc[1]       : 0.f;
    float v20 = (hp && wm) ? xc[ WW - 1] : 0.f;
    float v21 = (hp      ) ? xc[ WW    ] : 0.f;
    float v22 = (hp && wp) ? xc[ WW + 1] : 0.f;
    p[c]          = v11;
    p[CC + c]     = ((v02 - v00) + 2.f * (v12 - v10) + (v22 - v20)) * 0.125f;
    p[2 * CC + c] = ((v20 - v00) + 2.f * (v21 - v01) + (v22 - v02)) * 0.125f;
  }

  float upd[CC];
#pragma unroll
  for (int k = 0; k < CC; ++k) upd[k] = 0.f;

  const int row0 = q * 32;
#pragma unroll 2
  for (int o = 0; o < 32; ++o) {
    const int row = row0 + o;
    const float* wr = w1 + row * 48;     // wave-uniform -> s_load broadcast
    float a0 = b1[row], a1 = 0.f, a2 = 0.f, a3 = 0.f;
#pragma unroll
    for (int c = 0; c < 12; ++c) {
      a0 = fmaf(wr[c     ], p[c     ], a0);
      a1 = fmaf(wr[c + 12], p[c + 12], a1);
      a2 = fmaf(wr[c + 24], p[c + 24], a2);
      a3 = fmaf(wr[c + 36], p[c + 36], a3);
    }
    float y = (a0 + a1) + (a2 + a3);
    y = fmaxf(y, 0.f);                   // relu
    const float* w2r = w2t + row * CC;   // wave-uniform -> s_load broadcast
#pragma unroll
    for (int k = 0; k < CC; ++k) upd[k] = fmaf(w2r[k], y, upd[k]);
  }

  // ---- cross-wave (quarter) reduction via LDS, lane-contiguous (no conflicts)
#pragma unroll
  for (int k = 0; k < CC; ++k) red[q][k][lane] = upd[k];
  __syncthreads();

  const float fire = fire_val(ka, kb, (uint32_t)P);
  const int c0 = q * 4;                  // this wave finalizes 4 channels
#pragma unroll
  for (int cc = 0; cc < 4; ++cc) {
    const int c = c0 + cc;
    float s = red[0][c][lane] + red[1][c][lane] + red[2][c][lane]
            + red[3][c][lane] + b2[c];
    const int idx = b * CHW + c * HW + h * WW + w;
    raw[idx] = xcur[idx] + s * fire;     // xn (pre-life, pre-clip)
  }
}

// ---------------- Kernel B: life mask (3x3 maxpool on ch3) + clip ----------
__global__ __launch_bounds__(64) void ca_life(
    const float* __restrict__ xcur, const float* __restrict__ raw,
    float* __restrict__ xnext)
{
  const int P = blockIdx.x * 64 + threadIdx.x;
  const int b = P / HW;
  const int rem = P - b * HW;
  const int h = rem / WW;
  const int w = rem - h * WW;
  const bool hm = (h > 0), hp = (h < HH - 1), wm = (w > 0), wp = (w < WW - 1);
  const int base3 = b * CHW + 3 * HW + h * WW + w;

  float m1, m2;
  {
    const float* xc = xcur + base3;
    const float* xr = raw + base3;
    m1 = xc[0]; m2 = xr[0];
    if (hm) {
      m1 = fmaxf(m1, xc[-WW]); m2 = fmaxf(m2, xr[-WW]);
      if (wm) { m1 = fmaxf(m1, xc[-WW-1]); m2 = fmaxf(m2, xr[-WW-1]); }
      if (wp) { m1 = fmaxf(m1, xc[-WW+1]); m2 = fmaxf(m2, xr[-WW+1]); }
    }
    if (wm) { m1 = fmaxf(m1, xc[-1]); m2 = fmaxf(m2, xr[-1]); }
    if (wp) { m1 = fmaxf(m1, xc[ 1]); m2 = fmaxf(m2, xr[ 1]); }
    if (hp) {
      m1 = fmaxf(m1, xc[WW]); m2 = fmaxf(m2, xr[WW]);
      if (wm) { m1 = fmaxf(m1, xc[WW-1]); m2 = fmaxf(m2, xr[WW-1]); }
      if (wp) { m1 = fmaxf(m1, xc[WW+1]); m2 = fmaxf(m2, xr[WW+1]); }
    }
  }
  const float life = ((m1 > 0.1f) && (m2 > 0.1f)) ? 1.f : 0.f;

  const int base = b * CHW + h * WW + w;
#pragma unroll
  for (int c = 0; c < CC; ++c) {
    float v = raw[base + c * HW] * life;
    v = fminf(fmaxf(v, -10.f), 10.f);
    xnext[base + c * HW] = v;
  }
}

// ---------------- launcher ----------------
extern "C" void kernel_launch(void* const* d_in, const int* in_sizes, int n_in,
                              void* d_out, int out_size, void* d_ws, size_t ws_size,
                              hipStream_t stream) {
  const float* x  = (const float*)d_in[0];
  const float* w1 = (const float*)d_in[1];
  const float* b1 = (const float*)d_in[2];
  const float* w2 = (const float*)d_in[3];
  const float* b2 = (const float*)d_in[4];
  float* out = (float*)d_out;

  char* ws = (char*)d_ws;
  const size_t BUF = (size_t)NPIX * CC * sizeof(float);   // 4,718,592 B
  float* bufA   = (float*)(ws);
  float* bufRaw = (float*)(ws + BUF);
  float* w2t    = (float*)(ws + 2 * BUF);                 // 8 KiB

  hipLaunchKernelGGL(transp_w2, dim3(8), dim3(256), 0, stream, w2, w2t);

  const float* cur = x;
  for (int i = 0; i < STEPS; ++i) {
    uint32_t ka, kb;
    threefry2x32(0u, 42u, 0u, (uint32_t)i, ka, kb);       // fold_in(key(42), i)
    float* next = (i & 1) ? out : bufA;                   // step 15 (odd) -> out
    hipLaunchKernelGGL(ca_update, dim3(NPIX / 64), dim3(256), 0, stream,
                       cur, w1, b1, w2t, b2, bufRaw, ka, kb);
    hipLaunchKernelGGL(ca_life, dim3(NPIX / 64), dim3(64), 0, stream,
                       cur, bufRaw, next);
    cur = next;
  }
  (void)in_sizes; (void)n_in; (void)out_size; (void)ws_size;
}